// Round 21
// baseline (247.812 us; speedup 1.0000x reference)
//
#include <hip/hip_runtime.h>
#include <stdint.h>

namespace {

typedef unsigned long long ull;
constexpr int B = 4, C = 128, H = 256, W = 256;
constexpr int V = H * W;              // 65536
constexpr int E = 163072;             // 32640+32512+32640+32512+32768
constexpr long long CHW = (long long)C * V;
constexpr int ROUNDS = 17;
constexpr int NBLKV = (B * V) / 256;  // 1024 vertex blocks (256-thread kernels)
constexpr int SEG = 768;              // <=3 owned edges per vertex * 256

// Edge enumeration matches reference concat order: [L-vert, L-horiz, R-vert, R-horiz, cross]
__device__ __forceinline__ void edge_uv(int e, int& u, int& v) {
  if (e < 32640) {                       // L vertical
    int h = e >> 7, w = e & 127;
    u = (h << 8) + w; v = u + 256;
  } else if (e < 65152) {                // L horizontal
    int k = e - 32640; int h = k / 127, w = k - h * 127;
    u = (h << 8) + w; v = u + 1;
  } else if (e < 97792) {                // R vertical
    int k = e - 65152; int h = k >> 7, w = k & 127;
    u = (h << 8) + 128 + w; v = u + 256;
  } else if (e < 130304) {               // R horizontal
    int k = e - 97792; int h = k / 127, w = k - h * 127;
    u = (h << 8) + 128 + w; v = u + 1;
  } else {                               // cross
    int k = e - 130304; int h = k >> 7, w = k & 127;
    u = (h << 8) + w; v = u + 128;
  }
}

// Chase to effective root: self-loop, or min-id member of a 2-cycle
// (== reference cyc-break). Verified exact R1-R20. Tolerates concurrent
// COMPRESSION writes (par[x] := effective-root(x)); hooks stay phase-separated.
__device__ __forceinline__ int find_root(const int* __restrict__ par, int v) {
  int cur = v;
  int p = par[cur];
  for (int g = 0; g < 70000 && p != cur; ++g) {
    int gp = par[p];
    if (gp == cur) { cur = cur < p ? cur : p; break; }   // 2-cycle -> min id
    cur = p; p = gp;
  }
  return cur;
}

// Fused head, LDS-TILED. The head was invariant at ~76us across scalar/
// float2/float4 variants (R20 counters: VALU 13%, HBM 19%, Occ 16% -- pure
// per-wave load latency on the 256KB-strided c-planes). Fix: per 4-c group,
// cooperatively stage 4 planes x 5 rows (incl. dn halo) into LDS with 10
// back-to-back coalesced loads/thread (deep queue -> ONE ~900cyc latency per
// group instead of per-c), then compute from LDS. Values and fma order are
// BIT-IDENTICAL to the R13/R20-verified k_weight3 (same ascending-c chains).
__global__ __launch_bounds__(512)
void k_weight_t(const float* __restrict__ x, ull* __restrict__ wkey,
                float* __restrict__ out) {
  __shared__ float lds[4 * 5 * 256];                 // 20 KB: [c4][row5][w256]
  int blk = blockIdx.x;                              // = b*64 + h0/4
  int b = blk >> 6;
  int h0 = (blk & 63) << 2;
  int t = threadIdx.x;
  int row = t >> 7, q = t & 127;                     // row 0..3, q 0..127
  int h = h0 + row;
  int w0 = q << 1;
  bool isL  = q < 64;                                // wave-uniform
  bool hasV = h < 255;
  int roff = (isL ? (q < 63) : (q < 127)) ? 2 : 0;   // clamped when absent
  int drow = hasV ? row + 1 : row;                   // clamped dn row (in-tile)

  const float* xb = x + (long long)b * CHW;
  double n0x = 0, n0y = 0, ndnx = 0, ndny = 0, nrtx = 0, ncrx = 0, ncry = 0;
  double dv0 = 0, dv1 = 0, dh0 = 0, dh1 = 0, dx0 = 0, dx1 = 0;

  for (int c0 = 0; c0 < C; c0 += 4) {
    __syncthreads();                                 // prev group's reads done
    // stage: 4 c-planes x 5 rows x 256 floats = 5120 floats, 10/thread
#pragma unroll
    for (int i = 0; i < 10; ++i) {
      int f = (i << 9) + t;                          // 0..5119, coalesced
      int ci = f / 1280, rem = f - ci * 1280;
      int rr = rem >> 8, ww = rem & 255;
      int gh = h0 + rr; if (gh > 255) gh = 255;      // clamp halo row
      lds[f] = xb[(long long)(c0 + ci) * V + (gh << 8) + ww];
    }
    __syncthreads();
    // compute 4 c's from LDS (bit-identical chains, ascending c)
#pragma unroll
    for (int cc = 0; cc < 4; ++cc) {
      const float* base   = &lds[cc * 1280 + (row << 8)];
      const float* basedn = &lds[cc * 1280 + (drow << 8)];
      float2 a  = *(const float2*)(base + w0);
      float2 dn = *(const float2*)(basedn + w0);
      float2 rt = *(const float2*)(base + w0 + roff);
      if (isL) {
        float2 cr = *(const float2*)(base + w0 + 128);
        double ax = a.x, ay = a.y, dnx = dn.x, dny = dn.y, rtx = rt.x,
               crx = cr.x, cry = cr.y;
        n0x = fma(ax, ax, n0x);   n0y = fma(ay, ay, n0y);
        ndnx = fma(dnx, dnx, ndnx); ndny = fma(dny, dny, ndny);
        nrtx = fma(rtx, rtx, nrtx);
        ncrx = fma(crx, crx, ncrx); ncry = fma(cry, cry, ncry);
        dv0 = fma(ax, dnx, dv0);  dv1 = fma(ay, dny, dv1);
        dh0 = fma(ax, ay, dh0);   dh1 = fma(ay, rtx, dh1);
        dx0 = fma(ax, crx, dx0);  dx1 = fma(ay, cry, dx1);
      } else {
        double ax = a.x, ay = a.y, dnx = dn.x, dny = dn.y, rtx = rt.x;
        n0x = fma(ax, ax, n0x);   n0y = fma(ay, ay, n0y);
        ndnx = fma(dnx, dnx, ndnx); ndny = fma(dny, dny, ndny);
        nrtx = fma(rtx, rtx, nrtx);
        dv0 = fma(ax, dnx, dv0);  dv1 = fma(ay, dny, dv1);
        dh0 = fma(ax, ay, dh0);   dh1 = fma(ay, rtx, dh1);
      }
    }
  }

  ull* wk = wkey + (size_t)b * E;
  float* ob = out + (size_t)b * E;
  auto emit = [&](int e, double nu, double nv, double dot) {
    double denom = fmax(sqrt(nu) * sqrt(nv), 1e-8);
    float wv = (float)(dot / denom);
    unsigned int bits = __float_as_uint(wv);
    if (wv == 0.0f) bits = 0u;                       // collapse -0.0
    unsigned int mapped = bits ^ (((int)bits < 0) ? 0xFFFFFFFFu : 0x80000000u);
    wk[e] = ((ull)mapped << 32) | (unsigned int)e;
    ob[e] = 0.0f;
  };
  if (isL) {
    if (hasV) {
      emit((h << 7) + w0,     n0x, ndnx, dv0);
      emit((h << 7) + w0 + 1, n0y, ndny, dv1);
    }
    emit(32640 + h * 127 + w0, n0x, n0y, dh0);
    if (q < 63) emit(32640 + h * 127 + w0 + 1, n0y, nrtx, dh1);
    emit(130304 + (h << 7) + w0,     n0x, ncrx, dx0);
    emit(130304 + (h << 7) + w0 + 1, n0y, ncry, dx1);
  } else {
    int wr = w0 - 128;
    if (hasV) {
      emit(65152 + (h << 7) + wr,     n0x, ndnx, dv0);
      emit(65152 + (h << 7) + wr + 1, n0y, ndny, dv1);
    }
    emit(97792 + h * 127 + wr, n0x, n0y, dh0);
    if (q < 127) emit(97792 + h * 127 + wr + 1, n0y, nrtx, dh1);
  }
}

// Round 0 fused: local min over <=5 incident keys; mark + hook + arm BOTH
// minE buffers + flags init. (R20-verified; 1024-thread launch, idx-only.)
__global__ void k_r0(const ull* __restrict__ wkey, ull* __restrict__ minE0,
                     ull* __restrict__ minE1, int* __restrict__ parent,
                     float* __restrict__ out, int* __restrict__ flags) {
  int idx = blockIdx.x * blockDim.x + threadIdx.x;   // exact B*V grid
  int b = idx >> 16, v = idx & (V - 1);
  int h = v >> 8, w = v & 255;
  bool isL = w < 128;
  int wl = isL ? w : w - 128;
  int vb = isL ? 0 : 65152, hb = isL ? 32640 : 97792;
  const ull* wk = wkey + (size_t)b * E;
  ull m = ~0ULL;
  if (h > 0)    m = min(m, wk[vb + ((h - 1) << 7) + wl]);  // up
  if (h < 255)  m = min(m, wk[vb + (h << 7) + wl]);        // down
  if (wl > 0)   m = min(m, wk[hb + h * 127 + wl - 1]);     // left
  if (wl < 127) m = min(m, wk[hb + h * 127 + wl]);         // right
  m = min(m, wk[130304 + (h << 7) + wl]);                  // cross (both sides)
  int e = (int)(m & 0xFFFFFFFFu);
  int eu, ev; edge_uv(e, eu, ev);
  out[(size_t)b * E + e] = 1.0f;                     // winner (idempotent dup)
  parent[idx] = (v == eu) ? ev : eu;                 // hook to other endpoint
  minE0[idx] = ~0ULL;                                // arm buffer 0
  minE1[idx] = ~0ULL;                                // arm buffer 1
  if (idx < 32) flags[idx] = (idx <= 2) ? 1 : 0;
}

// Per-vertex root snapshot (coalesced first hop). Rounds 1 and 2.
__global__ void k_root(const int* __restrict__ parent, int* __restrict__ root) {
  int idx = blockIdx.x * blockDim.x + threadIdx.x;   // exact B*V grid
  int b = idx >> 16;
  root[idx] = find_root(parent + (b << 16), idx & (V - 1));
}

// Round 1 vmin. (R20-verified; 1024-thread launch, idx-only.)
__global__ void k_vminR1(const int* __restrict__ root, const ull* __restrict__ wkey,
                         ull* __restrict__ minE) {
  int idx = blockIdx.x * blockDim.x + threadIdx.x;   // exact B*V grid
  int b = idx >> 16, v = idx & (V - 1);
  int h = v >> 8, w = v & 255;
  bool isL = w < 128;
  int wl = isL ? w : w - 128;
  int vb = isL ? 0 : 65152, hb = isL ? 32640 : 97792;
  const int* rt = root + (b << 16);
  const ull* wk = wkey + (size_t)b * E;
  int rme = rt[v];
  ull m = ~0ULL;
  if (h > 0    && rt[v - 256] != rme) m = min(m, wk[vb + ((h - 1) << 7) + wl]);
  if (h < 255  && rt[v + 256] != rme) m = min(m, wk[vb + (h << 7) + wl]);
  if (wl > 0   && rt[v - 1]   != rme) m = min(m, wk[hb + h * 127 + wl - 1]);
  if (wl < 127 && rt[v + 1]   != rme) m = min(m, wk[hb + h * 127 + wl]);
  int xn = isL ? v + 128 : v - 128;
  if (rt[xn] != rme) m = min(m, wk[130304 + (h << 7) + wl]);
  if (m != ~0ULL) atomicMin(minE + (b << 16) + rme, m);  // fire-and-forget
}

// Round 2 vmin + owned-edge append (seeds round-3 frontier). UNCHANGED
// 256-thread structure (SEG/cntblk coupling). (R20-verified.)
__global__ void k_vminR2(const int* __restrict__ root, const ull* __restrict__ wkey,
                         ull* __restrict__ minE,
                         int* __restrict__ elseg, int* __restrict__ cntblk) {
  __shared__ int lcnt;
  if (threadIdx.x == 0) lcnt = 0;
  __syncthreads();
  int idx = blockIdx.x * blockDim.x + threadIdx.x;   // exact B*V grid
  int b = idx >> 16, v = idx & (V - 1);
  int h = v >> 8, w = v & 255;
  bool isL = w < 128;
  int wl = isL ? w : w - 128;
  int vb = isL ? 0 : 65152, hb = isL ? 32640 : 97792;
  const int* rt = root + (b << 16);
  const ull* wk = wkey + (size_t)b * E;
  int rme = rt[v];
  ull m = ~0ULL;
  int base = blockIdx.x * SEG;
  if (h > 0   && rt[v - 256] != rme) m = min(m, wk[vb + ((h - 1) << 7) + wl]);
  if (wl > 0  && rt[v - 1]   != rme) m = min(m, wk[hb + h * 127 + wl - 1]);
  if (!isL    && rt[v - 128] != rme) m = min(m, wk[130304 + (h << 7) + wl]);
  if (h < 255 && rt[v + 256] != rme) {
    int e = vb + (h << 7) + wl;
    m = min(m, wk[e]);
    elseg[base + atomicAdd(&lcnt, 1)] = e;
  }
  if (wl < 127 && rt[v + 1] != rme) {
    int e = hb + h * 127 + wl;
    m = min(m, wk[e]);
    elseg[base + atomicAdd(&lcnt, 1)] = e;
  }
  if (isL && rt[v + 128] != rme) {
    int e = 130304 + (h << 7) + wl;
    m = min(m, wk[e]);
    elseg[base + atomicAdd(&lcnt, 1)] = e;
  }
  if (m != ~0ULL) atomicMin(minE + (b << 16) + rme, m);  // fire-and-forget
  __syncthreads();
  if (threadIdx.x == 0) cntblk[blockIdx.x] = lcnt;
}

// Rounds 1-2 hook: winners + hook + FULL compression + re-arm.
// (R20-verified; 1024-thread launch, idx-only.)
__global__ void k_hookV(ull* __restrict__ minE, const int* __restrict__ root,
                        int* __restrict__ parent, float* __restrict__ out) {
  int idx = blockIdx.x * blockDim.x + threadIdx.x;   // exact B*V grid
  int b = idx >> 16, v = idx & (V - 1);
  int rr = root[idx];
  int np = rr;                                       // compression (non-roots)
  if (rr == v) {
    ull k = minE[idx];
    if (k != ~0ULL) {
      int e = (int)(k & 0xFFFFFFFFu);
      int eu, ev; edge_uv(e, eu, ev);
      const int* rt = root + (b << 16);
      int ru = rt[eu], rv2 = rt[ev];
      out[(size_t)b * E + e] = 1.0f;                 // winner (idempotent dup)
      np = (v == ru) ? rv2 : ru;                     // hook to other component
      minE[idx] = ~0ULL;                             // re-arm dirtied slot
    }
  }
  int* par = parent + (b << 16);
  if (par[v] != np) par[v] = np;
}

// Rounds 3..8 phase A + endpoint path compression. (R20-verified.)
__global__ void k_edgeA(int* __restrict__ parent, const ull* __restrict__ wkey,
                        ull* __restrict__ mcur, int* __restrict__ elseg,
                        unsigned int* __restrict__ prblk, int* __restrict__ cntblk,
                        int* __restrict__ flags, int r) {
  if (__hip_atomic_load(flags + r - 1, __ATOMIC_RELAXED,
                        __HIP_MEMORY_SCOPE_AGENT) == 0)
    return;                                          // converged
  int j = blockIdx.x, t = threadIdx.x;
  int n = cntblk[j];
  if (n == 0) return;                                // uniform per block
  __shared__ int lcnt;
  if (t == 0) lcnt = 0;
  int b = j >> 8;                                    // 256 vertex-blocks/batch
  int* par = parent + (b << 16);
  const ull* wk = wkey + (size_t)b * E;
  ull* mb = mcur + (b << 16);
  int base = j * SEG;
  int se[3]; unsigned int sp[3]; int ns = 0;
#pragma unroll
  for (int it = 0; it < 3; ++it) {                   // reads BEFORE barrier
    int i = t + (it << 8);
    if (i < n) {
      int e = elseg[base + i];
      int u, v; edge_uv(e, u, v);
      int ru = find_root(par, u);
      int rv = find_root(par, v);
      if (par[u] != ru) par[u] = ru;                 // compression (root-safe)
      if (par[v] != rv) par[v] = rv;
      if (ru != rv) {
        ull k = wk[e];
        atomicMin(mb + ru, k);                       // fire-and-forget
        atomicMin(mb + rv, k);
        se[ns] = e;
        sp[ns] = ((unsigned int)ru << 16) | (unsigned int)rv;
        ++ns;
      }
    }
  }
  __syncthreads();                                   // all reads done
  for (int i2 = 0; i2 < ns; ++i2) {
    int pos = atomicAdd(&lcnt, 1);                   // LDS, block-local
    elseg[base + pos] = se[i2];
    prblk[base + pos] = sp[i2];
  }
  __syncthreads();
  if (t == 0) {
    cntblk[j] = lcnt;
    if (lcnt &&
        __hip_atomic_load(flags + r, __ATOMIC_RELAXED, __HIP_MEMORY_SCOPE_AGENT) == 0)
      __hip_atomic_fetch_or(flags + r, 1, __ATOMIC_RELAXED, __HIP_MEMORY_SCOPE_AGENT);
  }
}

// Rounds 3..8 phase B. (R20-verified.)
__global__ void k_edgeB(const ull* __restrict__ mcur, ull* __restrict__ mnext,
                        const int* __restrict__ elseg,
                        const unsigned int* __restrict__ prblk,
                        const int* __restrict__ cntblk,
                        int* __restrict__ parent, float* __restrict__ out,
                        const int* __restrict__ flags, int r) {
  if (__hip_atomic_load(flags + r, __ATOMIC_RELAXED,
                        __HIP_MEMORY_SCOPE_AGENT) == 0)
    return;                                          // nothing kept this round
  int j = blockIdx.x, t = threadIdx.x;
  int n = cntblk[j];
  if (n == 0) return;
  int b = j >> 8;
  const ull* mbc = mcur + (b << 16);
  ull* mbn = mnext + (b << 16);
  int* par = parent + (b << 16);
  float* ob = out + (size_t)b * E;
  int base = j * SEG;
  for (int i = t; i < n; i += 256) {
    int e = elseg[base + i];
    unsigned int pr = prblk[base + i];
    int ru = (int)(pr >> 16), rv = (int)(pr & 0xFFFFu);
    ull mu = mbc[ru];                                // cross-dispatch: fresh
    ull mv = mbc[rv];
    bool wu = ((int)(mu & 0xFFFFFFFFu) == e);
    bool wv = ((int)(mv & 0xFFFFFFFFu) == e);
    if (wu | wv) ob[e] = 1.0f;                       // component min edge
    if (wu) par[ru] = rv;                            // unique writer per root
    if (wv) par[rv] = ru;                            // mutual -> 2-cycle
    mbn[ru] = ~0ULL;                                 // arm next buffer
    mbn[rv] = ~0ULL;                                 // (idempotent dups)
  }
}

// Rounds 9..16 in ONE dispatch: one 1024-thread block per batch.
// (R20-verified: out-of-place gather + endpoint compression.)
__global__ __launch_bounds__(1024)
void k_endgame(int* __restrict__ parent, ull* __restrict__ minE,
               const ull* __restrict__ wkey, float* __restrict__ out,
               const int* __restrict__ elseg, const int* __restrict__ cntblk,
               int* __restrict__ fe, unsigned int* __restrict__ fr) {
  int b = blockIdx.x, t = threadIdx.x;
  const ull* wk = wkey + (size_t)b * E;
  ull* mb = minE + (b << 16);
  int* par = parent + (b << 16);
  float* ob = out + (size_t)b * E;
  int* feb = fe + (size_t)b * E;                     // flat frontier (edges)
  unsigned int* frb = fr + (size_t)b * E;            // flat frontier (pairs)

  __shared__ int pre[257];
  __shared__ int wofs[16];
  __shared__ int s_wc;

  // gather segments into flat list, OUT-OF-PLACE (race-free: disjoint src/dst)
  if (t == 0) pre[0] = 0;
  if (t < 256) pre[t + 1] = cntblk[(b << 8) + t];
  __syncthreads();
  for (int ofs = 1; ofs < 256; ofs <<= 1) {          // inclusive scan
    int cur = 0, add = 0;
    if (t < 256) { cur = pre[t + 1]; if (t + 1 > ofs) add = pre[t + 1 - ofs]; }
    __syncthreads();
    if (t < 256) pre[t + 1] = cur + add;
    __syncthreads();
  }
  if (t < 256) {
    int dst = pre[t], cnt2 = pre[t + 1] - dst;
    int src = ((b << 8) + t) * SEG;
    for (int i = 0; i < cnt2; ++i) feb[dst + i] = elseg[src + i];
  }
  __syncthreads();
  int n = pre[256];

  for (int round = 9; round < ROUNDS && n > 0; ++round) {
    if (t == 0) s_wc = 0;
    __syncthreads();
    for (int base = 0; base < n; base += 1024) {
      int i = base + t;
      bool keep = false; int e = 0; unsigned int pr = 0;
      if (i < n) {
        e = feb[i];
        int u, v; edge_uv(e, u, v);
        int ru = find_root(par, u);
        int rv = find_root(par, v);
        if (par[u] != ru) par[u] = ru;               // compression (root-safe)
        if (par[v] != rv) par[v] = rv;
        if (ru != rv) {
          keep = true;
          pr = ((unsigned int)ru << 16) | (unsigned int)rv;
          ull k = wk[e];
          atomicMin(mb + ru, k);
          atomicMin(mb + rv, k);
        }
      }
      ull msk = __ballot(keep);
      int lane = t & 63, wid = t >> 6;
      if (lane == 0) wofs[wid] = (int)__popcll(msk);
      __syncthreads();                               // all reads of this chunk done
      if (t == 0) {
        int s = s_wc;
#pragma unroll
        for (int k2 = 0; k2 < 16; ++k2) { int c2 = wofs[k2]; wofs[k2] = s; s += c2; }
        s_wc = s;
      }
      __syncthreads();
      if (keep) {                                    // writes land < base+1024
        int pos = wofs[wid] + (int)__popcll(msk & ((1ULL << lane) - 1));
        feb[pos] = e;
        frb[pos] = pr;
      }
    }
    __syncthreads();
    int kept = s_wc;
    for (int i = t; i < kept; i += 1024) {           // winner-claim + hook
      unsigned int pr = frb[i];
      int ru = (int)(pr >> 16), rv = (int)(pr & 0xFFFFu);
      int e = feb[i];
      ull mu = __hip_atomic_load(mb + ru, __ATOMIC_RELAXED, __HIP_MEMORY_SCOPE_AGENT);
      ull mv = __hip_atomic_load(mb + rv, __ATOMIC_RELAXED, __HIP_MEMORY_SCOPE_AGENT);
      bool wu = ((int)(mu & 0xFFFFFFFFu) == e);
      bool wv = ((int)(mv & 0xFFFFFFFFu) == e);
      if (wu | wv) ob[e] = 1.0f;
      if (wu) par[ru] = rv;
      if (wv) par[rv] = ru;
    }
    __syncthreads();
    for (int i = t; i < kept; i += 1024) {           // re-arm dirtied slots
      unsigned int pr = frb[i];
      __hip_atomic_store(mb + (int)(pr >> 16), ~0ULL, __ATOMIC_RELAXED,
                         __HIP_MEMORY_SCOPE_AGENT);
      __hip_atomic_store(mb + (int)(pr & 0xFFFFu), ~0ULL, __ATOMIC_RELAXED,
                         __HIP_MEMORY_SCOPE_AGENT);
    }
    n = kept;
    __syncthreads();
  }
}

} // namespace

extern "C" void kernel_launch(void* const* d_in, const int* in_sizes, int n_in,
                              void* d_out, int out_size, void* d_ws, size_t ws_size,
                              hipStream_t stream) {
  const float* x = (const float*)d_in[0];
  float* out = (float*)d_out;

  char* ws = (char*)d_ws;
  size_t off = 0;
  auto alloc = [&](size_t bytes) {
    void* p = (void*)(ws + off);
    off += (bytes + 255) & ~(size_t)255;
    return p;
  };
  int* parent = (int*)alloc((size_t)B * V * sizeof(int));                      // 1 MB
  int* root   = (int*)alloc((size_t)B * V * sizeof(int));                      // 1 MB
  ull* minE0  = (ull*)alloc((size_t)B * V * 8);                                // 2 MB
  ull* minE1  = (ull*)alloc((size_t)B * V * 8);                                // 2 MB
  ull* wkey   = (ull*)alloc((size_t)B * E * 8);                                // ~5.2 MB
  int* elseg  = (int*)alloc((size_t)NBLKV * SEG * sizeof(int));                // 3 MB
  unsigned int* prblk = (unsigned int*)alloc((size_t)NBLKV * SEG * 4);         // 3 MB
  int* cntblk = (int*)alloc((size_t)NBLKV * sizeof(int));
  int* flags  = (int*)alloc(32 * sizeof(int));
  int* fe     = (int*)alloc((size_t)B * E * sizeof(int));                      // ~2.6 MB
  unsigned int* fr = (unsigned int*)alloc((size_t)B * E * 4);                  // ~2.6 MB

  // LDS-tiled head: 256 blocks of 512 (1/CU), 4 rows + halo per block
  k_weight_t<<<B * (H / 4), 512, 0, stream>>>(x, wkey, out);
  k_r0     <<<(B * V) / 1024, 1024, 0, stream>>>(wkey, minE0, minE1, parent, out, flags);

  // round 1 (per-vertex, minE0)
  k_root  <<<(B * V) / 1024, 1024, 0, stream>>>(parent, root);
  k_vminR1<<<(B * V) / 1024, 1024, 0, stream>>>(root, wkey, minE0);
  k_hookV <<<(B * V) / 1024, 1024, 0, stream>>>(minE0, root, parent, out);

  // round 2 (per-vertex, minE0; seeds round-3 edge frontier; 256-thread SEG)
  k_root  <<<(B * V) / 1024, 1024, 0, stream>>>(parent, root);
  k_vminR2<<<NBLKV, 256, 0, stream>>>(root, wkey, minE0, elseg, cntblk);
  k_hookV <<<(B * V) / 1024, 1024, 0, stream>>>(minE0, root, parent, out);

  // rounds 3..8 (edge frontier, double-buffered minE, endpoint compression)
  for (int r = 3; r <= 8; ++r) {
    ull* mcur  = (r & 1) ? minE0 : minE1;            // r3 -> minE0 (armed)
    ull* mnext = (r & 1) ? minE1 : minE0;
    k_edgeA<<<NBLKV, 256, 0, stream>>>(parent, wkey, mcur, elseg, prblk,
                                       cntblk, flags, r);
    k_edgeB<<<NBLKV, 256, 0, stream>>>(mcur, mnext, elseg, prblk, cntblk,
                                       parent, out, flags, r);
  }

  // rounds 9..16 in one dispatch (minE0 is the armed buffer at r9 entry)
  k_endgame<<<B, 1024, 0, stream>>>(parent, minE0, wkey, out, elseg, cntblk, fe, fr);
}

// Round 22
// 245.181 us; speedup vs baseline: 1.0107x; 1.0107x over previous
//
#include <hip/hip_runtime.h>
#include <stdint.h>

namespace {

typedef unsigned long long ull;
constexpr int B = 4, C = 128, H = 256, W = 256;
constexpr int V = H * W;              // 65536
constexpr int E = 163072;             // 32640+32512+32640+32512+32768
constexpr long long CHW = (long long)C * V;
constexpr int ROUNDS = 17;
constexpr int NBLKV = (B * V) / 256;  // 1024 vertex blocks (256-thread kernels)
constexpr int SEG = 768;              // <=3 owned edges per vertex * 256

// Edge enumeration matches reference concat order: [L-vert, L-horiz, R-vert, R-horiz, cross]
__device__ __forceinline__ void edge_uv(int e, int& u, int& v) {
  if (e < 32640) {                       // L vertical
    int h = e >> 7, w = e & 127;
    u = (h << 8) + w; v = u + 256;
  } else if (e < 65152) {                // L horizontal
    int k = e - 32640; int h = k / 127, w = k - h * 127;
    u = (h << 8) + w; v = u + 1;
  } else if (e < 97792) {                // R vertical
    int k = e - 65152; int h = k >> 7, w = k & 127;
    u = (h << 8) + 128 + w; v = u + 256;
  } else if (e < 130304) {               // R horizontal
    int k = e - 97792; int h = k / 127, w = k - h * 127;
    u = (h << 8) + 128 + w; v = u + 1;
  } else {                               // cross
    int k = e - 130304; int h = k >> 7, w = k & 127;
    u = (h << 8) + w; v = u + 128;
  }
}

// Chase to effective root: self-loop, or min-id member of a 2-cycle
// (== reference cyc-break). Verified exact R1-R21. Tolerates concurrent
// COMPRESSION writes (par[x] := effective-root(x)); hooks stay phase-separated.
__device__ __forceinline__ int find_root(const int* __restrict__ par, int v) {
  int cur = v;
  int p = par[cur];
  for (int g = 0; g < 70000 && p != cur; ++g) {
    int gp = par[p];
    if (gp == cur) { cur = cur < p ? cur : p; break; }   // 2-cycle -> min id
    cur = p; p = gp;
  }
  return cur;
}

// Fused head, SPLIT-C x4: 1024-thread block = 256 pixels (one row) x 4
// c-groups of 32 channels. The head was pinned at ~75us across 4 variants
// with <=16 waves/CU and nothing saturated (R20: VALU 13%, HBM 19%) --
// hypothesis: memory-level-parallelism cap. This config reaches 32 waves/CU
// (2 blocks x 16 waves, 56KB LDS each) and 4x outstanding loads. Per-group
// fp64 chains are the weight5 ascending-c chains over the group's 32 c's;
// groups are summed in fixed order S0+S1+S2+S3 (deterministic; fp64's 29
// guard bits make the fp32-rounded weight insensitive to this association).
__global__ __launch_bounds__(1024)
void k_weight6(const float* __restrict__ x, ull* __restrict__ wkey,
               float* __restrict__ out) {
  __shared__ double red[7][1024];                    // 56 KB
  int t = threadIdx.x;
  int g = t >> 8;                                    // c-group 0..3
  int lp = t & 255;                                  // pixel within row
  int gp = blockIdx.x * 256 + lp;                    // global pixel, [0, B*V)
  int b = gp >> 16, p = gp & (V - 1);
  int h = p >> 8, w = p & 255;
  bool isL = w < 128;
  int wl = isL ? w : w - 128;
  bool hasD = h < 255;
  bool hasR = wl < 127;
  int voff = hasD ? 256 : 0;                         // dummy when absent
  int roff = hasR ? 1 : 0;                           // dummy when absent
  int xoff = isL ? 128 : 0;                          // dummy for right half

  const float* xb = x + (long long)b * CHW + (long long)(g << 5) * V + p;
  double n0 = 0, ndn = 0, nrt = 0, ncr = 0, dd = 0, dr = 0, dx = 0;
#pragma unroll 4
  for (int c = 0; c < 32; ++c) {
    const float* pc = xb + (long long)c * V;
    double a  = (double)pc[0];
    double dn = (double)pc[voff];
    double rt = (double)pc[roff];
    double cr = (double)pc[xoff];
    n0  = fma(a, a, n0);
    ndn = fma(dn, dn, ndn);
    nrt = fma(rt, rt, nrt);
    ncr = fma(cr, cr, ncr);
    dd  = fma(a, dn, dd);
    dr  = fma(a, rt, dr);
    dx  = fma(a, cr, dx);
  }
  red[0][t] = n0;  red[1][t] = ndn; red[2][t] = nrt; red[3][t] = ncr;
  red[4][t] = dd;  red[5][t] = dr;  red[6][t] = dx;
  __syncthreads();

  if (g == 0) {
    double s[7];
#pragma unroll
    for (int q = 0; q < 7; ++q) {                    // fixed order: S0+S1+S2+S3
      double v0 = red[q][lp];
      v0 += red[q][lp + 256];
      v0 += red[q][lp + 512];
      v0 += red[q][lp + 768];
      s[q] = v0;
    }
    ull* wk = wkey + (size_t)b * E;
    float* ob = out + (size_t)b * E;
    auto emit = [&](int e, double nu, double nv, double dot) {
      double denom = fmax(sqrt(nu) * sqrt(nv), 1e-8);
      float wv = (float)(dot / denom);
      unsigned int bits = __float_as_uint(wv);
      if (wv == 0.0f) bits = 0u;                     // collapse -0.0
      unsigned int mapped = bits ^ (((int)bits < 0) ? 0xFFFFFFFFu : 0x80000000u);
      wk[e] = ((ull)mapped << 32) | (unsigned int)e;
      ob[e] = 0.0f;
    };
    int vb = isL ? 0 : 65152, hb = isL ? 32640 : 97792;
    if (hasD) emit(vb + (h << 7) + wl, s[0], s[1], s[4]);
    if (hasR) emit(hb + h * 127 + wl, s[0], s[2], s[5]);
    if (isL)  emit(130304 + (h << 7) + w, s[0], s[3], s[6]);
  }
}

// Round 0 fused: local min over <=5 incident keys; mark + hook + arm BOTH
// minE buffers + flags init. (R21-verified; 1024-thread launch, idx-only.)
__global__ void k_r0(const ull* __restrict__ wkey, ull* __restrict__ minE0,
                     ull* __restrict__ minE1, int* __restrict__ parent,
                     float* __restrict__ out, int* __restrict__ flags) {
  int idx = blockIdx.x * blockDim.x + threadIdx.x;   // exact B*V grid
  int b = idx >> 16, v = idx & (V - 1);
  int h = v >> 8, w = v & 255;
  bool isL = w < 128;
  int wl = isL ? w : w - 128;
  int vb = isL ? 0 : 65152, hb = isL ? 32640 : 97792;
  const ull* wk = wkey + (size_t)b * E;
  ull m = ~0ULL;
  if (h > 0)    m = min(m, wk[vb + ((h - 1) << 7) + wl]);  // up
  if (h < 255)  m = min(m, wk[vb + (h << 7) + wl]);        // down
  if (wl > 0)   m = min(m, wk[hb + h * 127 + wl - 1]);     // left
  if (wl < 127) m = min(m, wk[hb + h * 127 + wl]);         // right
  m = min(m, wk[130304 + (h << 7) + wl]);                  // cross (both sides)
  int e = (int)(m & 0xFFFFFFFFu);
  int eu, ev; edge_uv(e, eu, ev);
  out[(size_t)b * E + e] = 1.0f;                     // winner (idempotent dup)
  parent[idx] = (v == eu) ? ev : eu;                 // hook to other endpoint
  minE0[idx] = ~0ULL;                                // arm buffer 0
  minE1[idx] = ~0ULL;                                // arm buffer 1
  if (idx < 32) flags[idx] = (idx <= 2) ? 1 : 0;
}

// Per-vertex root snapshot (coalesced first hop). Rounds 1 and 2.
__global__ void k_root(const int* __restrict__ parent, int* __restrict__ root) {
  int idx = blockIdx.x * blockDim.x + threadIdx.x;   // exact B*V grid
  int b = idx >> 16;
  root[idx] = find_root(parent + (b << 16), idx & (V - 1));
}

// Round 1 vmin. (R21-verified; 1024-thread launch, idx-only.)
__global__ void k_vminR1(const int* __restrict__ root, const ull* __restrict__ wkey,
                         ull* __restrict__ minE) {
  int idx = blockIdx.x * blockDim.x + threadIdx.x;   // exact B*V grid
  int b = idx >> 16, v = idx & (V - 1);
  int h = v >> 8, w = v & 255;
  bool isL = w < 128;
  int wl = isL ? w : w - 128;
  int vb = isL ? 0 : 65152, hb = isL ? 32640 : 97792;
  const int* rt = root + (b << 16);
  const ull* wk = wkey + (size_t)b * E;
  int rme = rt[v];
  ull m = ~0ULL;
  if (h > 0    && rt[v - 256] != rme) m = min(m, wk[vb + ((h - 1) << 7) + wl]);
  if (h < 255  && rt[v + 256] != rme) m = min(m, wk[vb + (h << 7) + wl]);
  if (wl > 0   && rt[v - 1]   != rme) m = min(m, wk[hb + h * 127 + wl - 1]);
  if (wl < 127 && rt[v + 1]   != rme) m = min(m, wk[hb + h * 127 + wl]);
  int xn = isL ? v + 128 : v - 128;
  if (rt[xn] != rme) m = min(m, wk[130304 + (h << 7) + wl]);
  if (m != ~0ULL) atomicMin(minE + (b << 16) + rme, m);  // fire-and-forget
}

// Round 2 vmin + owned-edge append (seeds round-3 frontier). UNCHANGED
// 256-thread structure (SEG/cntblk coupling). (R21-verified.)
__global__ void k_vminR2(const int* __restrict__ root, const ull* __restrict__ wkey,
                         ull* __restrict__ minE,
                         int* __restrict__ elseg, int* __restrict__ cntblk) {
  __shared__ int lcnt;
  if (threadIdx.x == 0) lcnt = 0;
  __syncthreads();
  int idx = blockIdx.x * blockDim.x + threadIdx.x;   // exact B*V grid
  int b = idx >> 16, v = idx & (V - 1);
  int h = v >> 8, w = v & 255;
  bool isL = w < 128;
  int wl = isL ? w : w - 128;
  int vb = isL ? 0 : 65152, hb = isL ? 32640 : 97792;
  const int* rt = root + (b << 16);
  const ull* wk = wkey + (size_t)b * E;
  int rme = rt[v];
  ull m = ~0ULL;
  int base = blockIdx.x * SEG;
  if (h > 0   && rt[v - 256] != rme) m = min(m, wk[vb + ((h - 1) << 7) + wl]);
  if (wl > 0  && rt[v - 1]   != rme) m = min(m, wk[hb + h * 127 + wl - 1]);
  if (!isL    && rt[v - 128] != rme) m = min(m, wk[130304 + (h << 7) + wl]);
  if (h < 255 && rt[v + 256] != rme) {
    int e = vb + (h << 7) + wl;
    m = min(m, wk[e]);
    elseg[base + atomicAdd(&lcnt, 1)] = e;
  }
  if (wl < 127 && rt[v + 1] != rme) {
    int e = hb + h * 127 + wl;
    m = min(m, wk[e]);
    elseg[base + atomicAdd(&lcnt, 1)] = e;
  }
  if (isL && rt[v + 128] != rme) {
    int e = 130304 + (h << 7) + wl;
    m = min(m, wk[e]);
    elseg[base + atomicAdd(&lcnt, 1)] = e;
  }
  if (m != ~0ULL) atomicMin(minE + (b << 16) + rme, m);  // fire-and-forget
  __syncthreads();
  if (threadIdx.x == 0) cntblk[blockIdx.x] = lcnt;
}

// Rounds 1-2 hook: winners + hook + FULL compression + re-arm.
// (R21-verified; 1024-thread launch, idx-only.)
__global__ void k_hookV(ull* __restrict__ minE, const int* __restrict__ root,
                        int* __restrict__ parent, float* __restrict__ out) {
  int idx = blockIdx.x * blockDim.x + threadIdx.x;   // exact B*V grid
  int b = idx >> 16, v = idx & (V - 1);
  int rr = root[idx];
  int np = rr;                                       // compression (non-roots)
  if (rr == v) {
    ull k = minE[idx];
    if (k != ~0ULL) {
      int e = (int)(k & 0xFFFFFFFFu);
      int eu, ev; edge_uv(e, eu, ev);
      const int* rt = root + (b << 16);
      int ru = rt[eu], rv2 = rt[ev];
      out[(size_t)b * E + e] = 1.0f;                 // winner (idempotent dup)
      np = (v == ru) ? rv2 : ru;                     // hook to other component
      minE[idx] = ~0ULL;                             // re-arm dirtied slot
    }
  }
  int* par = parent + (b << 16);
  if (par[v] != np) par[v] = np;
}

// Rounds 3..8 phase A + endpoint path compression. (R21-verified.)
__global__ void k_edgeA(int* __restrict__ parent, const ull* __restrict__ wkey,
                        ull* __restrict__ mcur, int* __restrict__ elseg,
                        unsigned int* __restrict__ prblk, int* __restrict__ cntblk,
                        int* __restrict__ flags, int r) {
  if (__hip_atomic_load(flags + r - 1, __ATOMIC_RELAXED,
                        __HIP_MEMORY_SCOPE_AGENT) == 0)
    return;                                          // converged
  int j = blockIdx.x, t = threadIdx.x;
  int n = cntblk[j];
  if (n == 0) return;                                // uniform per block
  __shared__ int lcnt;
  if (t == 0) lcnt = 0;
  int b = j >> 8;                                    // 256 vertex-blocks/batch
  int* par = parent + (b << 16);
  const ull* wk = wkey + (size_t)b * E;
  ull* mb = mcur + (b << 16);
  int base = j * SEG;
  int se[3]; unsigned int sp[3]; int ns = 0;
#pragma unroll
  for (int it = 0; it < 3; ++it) {                   // reads BEFORE barrier
    int i = t + (it << 8);
    if (i < n) {
      int e = elseg[base + i];
      int u, v; edge_uv(e, u, v);
      int ru = find_root(par, u);
      int rv = find_root(par, v);
      if (par[u] != ru) par[u] = ru;                 // compression (root-safe)
      if (par[v] != rv) par[v] = rv;
      if (ru != rv) {
        ull k = wk[e];
        atomicMin(mb + ru, k);                       // fire-and-forget
        atomicMin(mb + rv, k);
        se[ns] = e;
        sp[ns] = ((unsigned int)ru << 16) | (unsigned int)rv;
        ++ns;
      }
    }
  }
  __syncthreads();                                   // all reads done
  for (int i2 = 0; i2 < ns; ++i2) {
    int pos = atomicAdd(&lcnt, 1);                   // LDS, block-local
    elseg[base + pos] = se[i2];
    prblk[base + pos] = sp[i2];
  }
  __syncthreads();
  if (t == 0) {
    cntblk[j] = lcnt;
    if (lcnt &&
        __hip_atomic_load(flags + r, __ATOMIC_RELAXED, __HIP_MEMORY_SCOPE_AGENT) == 0)
      __hip_atomic_fetch_or(flags + r, 1, __ATOMIC_RELAXED, __HIP_MEMORY_SCOPE_AGENT);
  }
}

// Rounds 3..8 phase B. (R21-verified.)
__global__ void k_edgeB(const ull* __restrict__ mcur, ull* __restrict__ mnext,
                        const int* __restrict__ elseg,
                        const unsigned int* __restrict__ prblk,
                        const int* __restrict__ cntblk,
                        int* __restrict__ parent, float* __restrict__ out,
                        const int* __restrict__ flags, int r) {
  if (__hip_atomic_load(flags + r, __ATOMIC_RELAXED,
                        __HIP_MEMORY_SCOPE_AGENT) == 0)
    return;                                          // nothing kept this round
  int j = blockIdx.x, t = threadIdx.x;
  int n = cntblk[j];
  if (n == 0) return;
  int b = j >> 8;
  const ull* mbc = mcur + (b << 16);
  ull* mbn = mnext + (b << 16);
  int* par = parent + (b << 16);
  float* ob = out + (size_t)b * E;
  int base = j * SEG;
  for (int i = t; i < n; i += 256) {
    int e = elseg[base + i];
    unsigned int pr = prblk[base + i];
    int ru = (int)(pr >> 16), rv = (int)(pr & 0xFFFFu);
    ull mu = mbc[ru];                                // cross-dispatch: fresh
    ull mv = mbc[rv];
    bool wu = ((int)(mu & 0xFFFFFFFFu) == e);
    bool wv = ((int)(mv & 0xFFFFFFFFu) == e);
    if (wu | wv) ob[e] = 1.0f;                       // component min edge
    if (wu) par[ru] = rv;                            // unique writer per root
    if (wv) par[rv] = ru;                            // mutual -> 2-cycle
    mbn[ru] = ~0ULL;                                 // arm next buffer
    mbn[rv] = ~0ULL;                                 // (idempotent dups)
  }
}

// Rounds 9..16 in ONE dispatch: one 1024-thread block per batch.
// (R21-verified: out-of-place gather + endpoint compression.)
__global__ __launch_bounds__(1024)
void k_endgame(int* __restrict__ parent, ull* __restrict__ minE,
               const ull* __restrict__ wkey, float* __restrict__ out,
               const int* __restrict__ elseg, const int* __restrict__ cntblk,
               int* __restrict__ fe, unsigned int* __restrict__ fr) {
  int b = blockIdx.x, t = threadIdx.x;
  const ull* wk = wkey + (size_t)b * E;
  ull* mb = minE + (b << 16);
  int* par = parent + (b << 16);
  float* ob = out + (size_t)b * E;
  int* feb = fe + (size_t)b * E;                     // flat frontier (edges)
  unsigned int* frb = fr + (size_t)b * E;            // flat frontier (pairs)

  __shared__ int pre[257];
  __shared__ int wofs[16];
  __shared__ int s_wc;

  // gather segments into flat list, OUT-OF-PLACE (race-free: disjoint src/dst)
  if (t == 0) pre[0] = 0;
  if (t < 256) pre[t + 1] = cntblk[(b << 8) + t];
  __syncthreads();
  for (int ofs = 1; ofs < 256; ofs <<= 1) {          // inclusive scan
    int cur = 0, add = 0;
    if (t < 256) { cur = pre[t + 1]; if (t + 1 > ofs) add = pre[t + 1 - ofs]; }
    __syncthreads();
    if (t < 256) pre[t + 1] = cur + add;
    __syncthreads();
  }
  if (t < 256) {
    int dst = pre[t], cnt2 = pre[t + 1] - dst;
    int src = ((b << 8) + t) * SEG;
    for (int i = 0; i < cnt2; ++i) feb[dst + i] = elseg[src + i];
  }
  __syncthreads();
  int n = pre[256];

  for (int round = 9; round < ROUNDS && n > 0; ++round) {
    if (t == 0) s_wc = 0;
    __syncthreads();
    for (int base = 0; base < n; base += 1024) {
      int i = base + t;
      bool keep = false; int e = 0; unsigned int pr = 0;
      if (i < n) {
        e = feb[i];
        int u, v; edge_uv(e, u, v);
        int ru = find_root(par, u);
        int rv = find_root(par, v);
        if (par[u] != ru) par[u] = ru;               // compression (root-safe)
        if (par[v] != rv) par[v] = rv;
        if (ru != rv) {
          keep = true;
          pr = ((unsigned int)ru << 16) | (unsigned int)rv;
          ull k = wk[e];
          atomicMin(mb + ru, k);
          atomicMin(mb + rv, k);
        }
      }
      ull msk = __ballot(keep);
      int lane = t & 63, wid = t >> 6;
      if (lane == 0) wofs[wid] = (int)__popcll(msk);
      __syncthreads();                               // all reads of this chunk done
      if (t == 0) {
        int s = s_wc;
#pragma unroll
        for (int k2 = 0; k2 < 16; ++k2) { int c2 = wofs[k2]; wofs[k2] = s; s += c2; }
        s_wc = s;
      }
      __syncthreads();
      if (keep) {                                    // writes land < base+1024
        int pos = wofs[wid] + (int)__popcll(msk & ((1ULL << lane) - 1));
        feb[pos] = e;
        frb[pos] = pr;
      }
    }
    __syncthreads();
    int kept = s_wc;
    for (int i = t; i < kept; i += 1024) {           // winner-claim + hook
      unsigned int pr = frb[i];
      int ru = (int)(pr >> 16), rv = (int)(pr & 0xFFFFu);
      int e = feb[i];
      ull mu = __hip_atomic_load(mb + ru, __ATOMIC_RELAXED, __HIP_MEMORY_SCOPE_AGENT);
      ull mv = __hip_atomic_load(mb + rv, __ATOMIC_RELAXED, __HIP_MEMORY_SCOPE_AGENT);
      bool wu = ((int)(mu & 0xFFFFFFFFu) == e);
      bool wv = ((int)(mv & 0xFFFFFFFFu) == e);
      if (wu | wv) ob[e] = 1.0f;
      if (wu) par[ru] = rv;
      if (wv) par[rv] = ru;
    }
    __syncthreads();
    for (int i = t; i < kept; i += 1024) {           // re-arm dirtied slots
      unsigned int pr = frb[i];
      __hip_atomic_store(mb + (int)(pr >> 16), ~0ULL, __ATOMIC_RELAXED,
                         __HIP_MEMORY_SCOPE_AGENT);
      __hip_atomic_store(mb + (int)(pr & 0xFFFFu), ~0ULL, __ATOMIC_RELAXED,
                         __HIP_MEMORY_SCOPE_AGENT);
    }
    n = kept;
    __syncthreads();
  }
}

} // namespace

extern "C" void kernel_launch(void* const* d_in, const int* in_sizes, int n_in,
                              void* d_out, int out_size, void* d_ws, size_t ws_size,
                              hipStream_t stream) {
  const float* x = (const float*)d_in[0];
  float* out = (float*)d_out;

  char* ws = (char*)d_ws;
  size_t off = 0;
  auto alloc = [&](size_t bytes) {
    void* p = (void*)(ws + off);
    off += (bytes + 255) & ~(size_t)255;
    return p;
  };
  int* parent = (int*)alloc((size_t)B * V * sizeof(int));                      // 1 MB
  int* root   = (int*)alloc((size_t)B * V * sizeof(int));                      // 1 MB
  ull* minE0  = (ull*)alloc((size_t)B * V * 8);                                // 2 MB
  ull* minE1  = (ull*)alloc((size_t)B * V * 8);                                // 2 MB
  ull* wkey   = (ull*)alloc((size_t)B * E * 8);                                // ~5.2 MB
  int* elseg  = (int*)alloc((size_t)NBLKV * SEG * sizeof(int));                // 3 MB
  unsigned int* prblk = (unsigned int*)alloc((size_t)NBLKV * SEG * 4);         // 3 MB
  int* cntblk = (int*)alloc((size_t)NBLKV * sizeof(int));
  int* flags  = (int*)alloc(32 * sizeof(int));
  int* fe     = (int*)alloc((size_t)B * E * sizeof(int));                      // ~2.6 MB
  unsigned int* fr = (unsigned int*)alloc((size_t)B * E * 4);                  // ~2.6 MB

  // split-C head: 1024 blocks of 1024 (256 pixels x 4 c-groups), 2 blocks/CU
  k_weight6<<<(B * V) / 256, 1024, 0, stream>>>(x, wkey, out);
  k_r0     <<<(B * V) / 1024, 1024, 0, stream>>>(wkey, minE0, minE1, parent, out, flags);

  // round 1 (per-vertex, minE0)
  k_root  <<<(B * V) / 1024, 1024, 0, stream>>>(parent, root);
  k_vminR1<<<(B * V) / 1024, 1024, 0, stream>>>(root, wkey, minE0);
  k_hookV <<<(B * V) / 1024, 1024, 0, stream>>>(minE0, root, parent, out);

  // round 2 (per-vertex, minE0; seeds round-3 edge frontier; 256-thread SEG)
  k_root  <<<(B * V) / 1024, 1024, 0, stream>>>(parent, root);
  k_vminR2<<<NBLKV, 256, 0, stream>>>(root, wkey, minE0, elseg, cntblk);
  k_hookV <<<(B * V) / 1024, 1024, 0, stream>>>(minE0, root, parent, out);

  // rounds 3..8 (edge frontier, double-buffered minE, endpoint compression)
  for (int r = 3; r <= 8; ++r) {
    ull* mcur  = (r & 1) ? minE0 : minE1;            // r3 -> minE0 (armed)
    ull* mnext = (r & 1) ? minE1 : minE0;
    k_edgeA<<<NBLKV, 256, 0, stream>>>(parent, wkey, mcur, elseg, prblk,
                                       cntblk, flags, r);
    k_edgeB<<<NBLKV, 256, 0, stream>>>(mcur, mnext, elseg, prblk, cntblk,
                                       parent, out, flags, r);
  }

  // rounds 9..16 in one dispatch (minE0 is the armed buffer at r9 entry)
  k_endgame<<<B, 1024, 0, stream>>>(parent, minE0, wkey, out, elseg, cntblk, fe, fr);
}

// Round 23
// 236.951 us; speedup vs baseline: 1.0458x; 1.0347x over previous
//
#include <hip/hip_runtime.h>
#include <stdint.h>

namespace {

typedef unsigned long long ull;
constexpr int B = 4, C = 128, H = 256, W = 256;
constexpr int V = H * W;              // 65536
constexpr int E = 163072;             // 32640+32512+32640+32512+32768
constexpr long long CHW = (long long)C * V;
constexpr int ROUNDS = 17;
constexpr int NBLKV = (B * V) / 256;  // 1024 vertex blocks (256-thread kernels)
constexpr int SEG = 768;              // <=3 owned edges per vertex * 256

// Edge enumeration matches reference concat order: [L-vert, L-horiz, R-vert, R-horiz, cross]
__device__ __forceinline__ void edge_uv(int e, int& u, int& v) {
  if (e < 32640) {                       // L vertical
    int h = e >> 7, w = e & 127;
    u = (h << 8) + w; v = u + 256;
  } else if (e < 65152) {                // L horizontal
    int k = e - 32640; int h = k / 127, w = k - h * 127;
    u = (h << 8) + w; v = u + 1;
  } else if (e < 97792) {                // R vertical
    int k = e - 65152; int h = k >> 7, w = k & 127;
    u = (h << 8) + 128 + w; v = u + 256;
  } else if (e < 130304) {               // R horizontal
    int k = e - 97792; int h = k / 127, w = k - h * 127;
    u = (h << 8) + 128 + w; v = u + 1;
  } else {                               // cross
    int k = e - 130304; int h = k >> 7, w = k & 127;
    u = (h << 8) + w; v = u + 128;
  }
}

// Chase to effective root: self-loop, or min-id member of a 2-cycle
// (== reference cyc-break). Verified exact R1-R22. Tolerates concurrent
// COMPRESSION writes (par[x] := effective-root(x)); hooks stay phase-separated.
__device__ __forceinline__ int find_root(const int* __restrict__ par, int v) {
  int cur = v;
  int p = par[cur];
  for (int g = 0; g < 70000 && p != cur; ++g) {
    int gp = par[p];
    if (gp == cur) { cur = cur < p ? cur : p; break; }   // 2-cycle -> min id
    cur = p; p = gp;
  }
  return cur;
}

// Fused head (R19-verified best config: 237.1us total). Per-pixel threads,
// single-body branch-free c-loop with clamped dummy offsets; 1024-thread
// blocks = 4 consecutive rows per block for dn-stream cache reuse.
// HEAD CEILING NOTE: five structurally distinct variants (scalar/float2/
// float4/LDS-tiled/split-C) all measure 70-76us -- the 4-5-way strided
// plane-stream pattern caps at ~1.5-1.9 TB/s on this chip regardless of
// occupancy/vectorization/MLP. This is the pattern's platform floor.
__global__ void k_weight5(const float* __restrict__ x, ull* __restrict__ wkey,
                          float* __restrict__ out) {
  int idx = blockIdx.x * blockDim.x + threadIdx.x;   // exact B*V grid
  int b = idx >> 16, p = idx & (V - 1);
  int h = p >> 8, w = p & 255;
  bool isL = w < 128;
  int wl = isL ? w : w - 128;
  bool hasD = h < 255;
  bool hasR = wl < 127;                              // horiz edge within half
  int voff = hasD ? 256 : 0;                         // dummy when absent
  int roff = hasR ? 1 : 0;                           // dummy when absent
  int xoff = isL ? 128 : 0;                          // dummy for right half

  const float* xb = x + (long long)b * CHW + p;
  double n0 = 0, ndn = 0, nrt = 0, ncr = 0, dd = 0, dr = 0, dx = 0;
#pragma unroll 4
  for (int c = 0; c < C; ++c) {
    const float* pc = xb + (long long)c * V;
    double a  = (double)pc[0];
    double dn = (double)pc[voff];
    double rt = (double)pc[roff];
    double cr = (double)pc[xoff];
    n0  = fma(a, a, n0);
    ndn = fma(dn, dn, ndn);
    nrt = fma(rt, rt, nrt);
    ncr = fma(cr, cr, ncr);
    dd  = fma(a, dn, dd);
    dr  = fma(a, rt, dr);
    dx  = fma(a, cr, dx);
  }

  ull* wk = wkey + (size_t)b * E;
  float* ob = out + (size_t)b * E;
  auto emit = [&](int e, double nu, double nv, double dot) {
    double denom = fmax(sqrt(nu) * sqrt(nv), 1e-8);
    float wv = (float)(dot / denom);
    unsigned int bits = __float_as_uint(wv);
    if (wv == 0.0f) bits = 0u;                       // collapse -0.0
    unsigned int mapped = bits ^ (((int)bits < 0) ? 0xFFFFFFFFu : 0x80000000u);
    wk[e] = ((ull)mapped << 32) | (unsigned int)e;
    ob[e] = 0.0f;
  };
  int vb = isL ? 0 : 65152, hb = isL ? 32640 : 97792;
  if (hasD) emit(vb + (h << 7) + wl, n0, ndn, dd);
  if (hasR) emit(hb + h * 127 + wl, n0, nrt, dr);
  if (isL)  emit(130304 + (h << 7) + w, n0, ncr, dx);
}

// Round 0 fused: local min over <=5 incident keys; mark + hook + arm BOTH
// minE buffers + flags init. (R19-verified; 1024-thread launch, idx-only.)
__global__ void k_r0(const ull* __restrict__ wkey, ull* __restrict__ minE0,
                     ull* __restrict__ minE1, int* __restrict__ parent,
                     float* __restrict__ out, int* __restrict__ flags) {
  int idx = blockIdx.x * blockDim.x + threadIdx.x;   // exact B*V grid
  int b = idx >> 16, v = idx & (V - 1);
  int h = v >> 8, w = v & 255;
  bool isL = w < 128;
  int wl = isL ? w : w - 128;
  int vb = isL ? 0 : 65152, hb = isL ? 32640 : 97792;
  const ull* wk = wkey + (size_t)b * E;
  ull m = ~0ULL;
  if (h > 0)    m = min(m, wk[vb + ((h - 1) << 7) + wl]);  // up
  if (h < 255)  m = min(m, wk[vb + (h << 7) + wl]);        // down
  if (wl > 0)   m = min(m, wk[hb + h * 127 + wl - 1]);     // left
  if (wl < 127) m = min(m, wk[hb + h * 127 + wl]);         // right
  m = min(m, wk[130304 + (h << 7) + wl]);                  // cross (both sides)
  int e = (int)(m & 0xFFFFFFFFu);
  int eu, ev; edge_uv(e, eu, ev);
  out[(size_t)b * E + e] = 1.0f;                     // winner (idempotent dup)
  parent[idx] = (v == eu) ? ev : eu;                 // hook to other endpoint
  minE0[idx] = ~0ULL;                                // arm buffer 0
  minE1[idx] = ~0ULL;                                // arm buffer 1
  if (idx < 32) flags[idx] = (idx <= 2) ? 1 : 0;
}

// Per-vertex root snapshot (coalesced first hop). Rounds 1 and 2.
__global__ void k_root(const int* __restrict__ parent, int* __restrict__ root) {
  int idx = blockIdx.x * blockDim.x + threadIdx.x;   // exact B*V grid
  int b = idx >> 16;
  root[idx] = find_root(parent + (b << 16), idx & (V - 1));
}

// Round 1 vmin. (R19-verified; 1024-thread launch, idx-only.)
__global__ void k_vminR1(const int* __restrict__ root, const ull* __restrict__ wkey,
                         ull* __restrict__ minE) {
  int idx = blockIdx.x * blockDim.x + threadIdx.x;   // exact B*V grid
  int b = idx >> 16, v = idx & (V - 1);
  int h = v >> 8, w = v & 255;
  bool isL = w < 128;
  int wl = isL ? w : w - 128;
  int vb = isL ? 0 : 65152, hb = isL ? 32640 : 97792;
  const int* rt = root + (b << 16);
  const ull* wk = wkey + (size_t)b * E;
  int rme = rt[v];
  ull m = ~0ULL;
  if (h > 0    && rt[v - 256] != rme) m = min(m, wk[vb + ((h - 1) << 7) + wl]);
  if (h < 255  && rt[v + 256] != rme) m = min(m, wk[vb + (h << 7) + wl]);
  if (wl > 0   && rt[v - 1]   != rme) m = min(m, wk[hb + h * 127 + wl - 1]);
  if (wl < 127 && rt[v + 1]   != rme) m = min(m, wk[hb + h * 127 + wl]);
  int xn = isL ? v + 128 : v - 128;
  if (rt[xn] != rme) m = min(m, wk[130304 + (h << 7) + wl]);
  if (m != ~0ULL) atomicMin(minE + (b << 16) + rme, m);  // fire-and-forget
}

// Round 2 vmin + owned-edge append (seeds round-3 frontier). UNCHANGED
// 256-thread structure (SEG/cntblk coupling). (R19-verified.)
__global__ void k_vminR2(const int* __restrict__ root, const ull* __restrict__ wkey,
                         ull* __restrict__ minE,
                         int* __restrict__ elseg, int* __restrict__ cntblk) {
  __shared__ int lcnt;
  if (threadIdx.x == 0) lcnt = 0;
  __syncthreads();
  int idx = blockIdx.x * blockDim.x + threadIdx.x;   // exact B*V grid
  int b = idx >> 16, v = idx & (V - 1);
  int h = v >> 8, w = v & 255;
  bool isL = w < 128;
  int wl = isL ? w : w - 128;
  int vb = isL ? 0 : 65152, hb = isL ? 32640 : 97792;
  const int* rt = root + (b << 16);
  const ull* wk = wkey + (size_t)b * E;
  int rme = rt[v];
  ull m = ~0ULL;
  int base = blockIdx.x * SEG;
  if (h > 0   && rt[v - 256] != rme) m = min(m, wk[vb + ((h - 1) << 7) + wl]);
  if (wl > 0  && rt[v - 1]   != rme) m = min(m, wk[hb + h * 127 + wl - 1]);
  if (!isL    && rt[v - 128] != rme) m = min(m, wk[130304 + (h << 7) + wl]);
  if (h < 255 && rt[v + 256] != rme) {
    int e = vb + (h << 7) + wl;
    m = min(m, wk[e]);
    elseg[base + atomicAdd(&lcnt, 1)] = e;
  }
  if (wl < 127 && rt[v + 1] != rme) {
    int e = hb + h * 127 + wl;
    m = min(m, wk[e]);
    elseg[base + atomicAdd(&lcnt, 1)] = e;
  }
  if (isL && rt[v + 128] != rme) {
    int e = 130304 + (h << 7) + wl;
    m = min(m, wk[e]);
    elseg[base + atomicAdd(&lcnt, 1)] = e;
  }
  if (m != ~0ULL) atomicMin(minE + (b << 16) + rme, m);  // fire-and-forget
  __syncthreads();
  if (threadIdx.x == 0) cntblk[blockIdx.x] = lcnt;
}

// Rounds 1-2 hook: winners + hook + FULL compression + re-arm.
// (R19-verified; 1024-thread launch, idx-only.)
__global__ void k_hookV(ull* __restrict__ minE, const int* __restrict__ root,
                        int* __restrict__ parent, float* __restrict__ out) {
  int idx = blockIdx.x * blockDim.x + threadIdx.x;   // exact B*V grid
  int b = idx >> 16, v = idx & (V - 1);
  int rr = root[idx];
  int np = rr;                                       // compression (non-roots)
  if (rr == v) {
    ull k = minE[idx];
    if (k != ~0ULL) {
      int e = (int)(k & 0xFFFFFFFFu);
      int eu, ev; edge_uv(e, eu, ev);
      const int* rt = root + (b << 16);
      int ru = rt[eu], rv2 = rt[ev];
      out[(size_t)b * E + e] = 1.0f;                 // winner (idempotent dup)
      np = (v == ru) ? rv2 : ru;                     // hook to other component
      minE[idx] = ~0ULL;                             // re-arm dirtied slot
    }
  }
  int* par = parent + (b << 16);
  if (par[v] != np) par[v] = np;
}

// Rounds 3..8 phase A + endpoint path compression. (R19-verified.)
__global__ void k_edgeA(int* __restrict__ parent, const ull* __restrict__ wkey,
                        ull* __restrict__ mcur, int* __restrict__ elseg,
                        unsigned int* __restrict__ prblk, int* __restrict__ cntblk,
                        int* __restrict__ flags, int r) {
  if (__hip_atomic_load(flags + r - 1, __ATOMIC_RELAXED,
                        __HIP_MEMORY_SCOPE_AGENT) == 0)
    return;                                          // converged
  int j = blockIdx.x, t = threadIdx.x;
  int n = cntblk[j];
  if (n == 0) return;                                // uniform per block
  __shared__ int lcnt;
  if (t == 0) lcnt = 0;
  int b = j >> 8;                                    // 256 vertex-blocks/batch
  int* par = parent + (b << 16);
  const ull* wk = wkey + (size_t)b * E;
  ull* mb = mcur + (b << 16);
  int base = j * SEG;
  int se[3]; unsigned int sp[3]; int ns = 0;
#pragma unroll
  for (int it = 0; it < 3; ++it) {                   // reads BEFORE barrier
    int i = t + (it << 8);
    if (i < n) {
      int e = elseg[base + i];
      int u, v; edge_uv(e, u, v);
      int ru = find_root(par, u);
      int rv = find_root(par, v);
      if (par[u] != ru) par[u] = ru;                 // compression (root-safe)
      if (par[v] != rv) par[v] = rv;
      if (ru != rv) {
        ull k = wk[e];
        atomicMin(mb + ru, k);                       // fire-and-forget
        atomicMin(mb + rv, k);
        se[ns] = e;
        sp[ns] = ((unsigned int)ru << 16) | (unsigned int)rv;
        ++ns;
      }
    }
  }
  __syncthreads();                                   // all reads done
  for (int i2 = 0; i2 < ns; ++i2) {
    int pos = atomicAdd(&lcnt, 1);                   // LDS, block-local
    elseg[base + pos] = se[i2];
    prblk[base + pos] = sp[i2];
  }
  __syncthreads();
  if (t == 0) {
    cntblk[j] = lcnt;
    if (lcnt &&
        __hip_atomic_load(flags + r, __ATOMIC_RELAXED, __HIP_MEMORY_SCOPE_AGENT) == 0)
      __hip_atomic_fetch_or(flags + r, 1, __ATOMIC_RELAXED, __HIP_MEMORY_SCOPE_AGENT);
  }
}

// Rounds 3..8 phase B. (R19-verified.)
__global__ void k_edgeB(const ull* __restrict__ mcur, ull* __restrict__ mnext,
                        const int* __restrict__ elseg,
                        const unsigned int* __restrict__ prblk,
                        const int* __restrict__ cntblk,
                        int* __restrict__ parent, float* __restrict__ out,
                        const int* __restrict__ flags, int r) {
  if (__hip_atomic_load(flags + r, __ATOMIC_RELAXED,
                        __HIP_MEMORY_SCOPE_AGENT) == 0)
    return;                                          // nothing kept this round
  int j = blockIdx.x, t = threadIdx.x;
  int n = cntblk[j];
  if (n == 0) return;
  int b = j >> 8;
  const ull* mbc = mcur + (b << 16);
  ull* mbn = mnext + (b << 16);
  int* par = parent + (b << 16);
  float* ob = out + (size_t)b * E;
  int base = j * SEG;
  for (int i = t; i < n; i += 256) {
    int e = elseg[base + i];
    unsigned int pr = prblk[base + i];
    int ru = (int)(pr >> 16), rv = (int)(pr & 0xFFFFu);
    ull mu = mbc[ru];                                // cross-dispatch: fresh
    ull mv = mbc[rv];
    bool wu = ((int)(mu & 0xFFFFFFFFu) == e);
    bool wv = ((int)(mv & 0xFFFFFFFFu) == e);
    if (wu | wv) ob[e] = 1.0f;                       // component min edge
    if (wu) par[ru] = rv;                            // unique writer per root
    if (wv) par[rv] = ru;                            // mutual -> 2-cycle
    mbn[ru] = ~0ULL;                                 // arm next buffer
    mbn[rv] = ~0ULL;                                 // (idempotent dups)
  }
}

// Rounds 9..16 in ONE dispatch: one 1024-thread block per batch.
// (R19-verified: out-of-place gather + endpoint compression.)
__global__ __launch_bounds__(1024)
void k_endgame(int* __restrict__ parent, ull* __restrict__ minE,
               const ull* __restrict__ wkey, float* __restrict__ out,
               const int* __restrict__ elseg, const int* __restrict__ cntblk,
               int* __restrict__ fe, unsigned int* __restrict__ fr) {
  int b = blockIdx.x, t = threadIdx.x;
  const ull* wk = wkey + (size_t)b * E;
  ull* mb = minE + (b << 16);
  int* par = parent + (b << 16);
  float* ob = out + (size_t)b * E;
  int* feb = fe + (size_t)b * E;                     // flat frontier (edges)
  unsigned int* frb = fr + (size_t)b * E;            // flat frontier (pairs)

  __shared__ int pre[257];
  __shared__ int wofs[16];
  __shared__ int s_wc;

  // gather segments into flat list, OUT-OF-PLACE (race-free: disjoint src/dst)
  if (t == 0) pre[0] = 0;
  if (t < 256) pre[t + 1] = cntblk[(b << 8) + t];
  __syncthreads();
  for (int ofs = 1; ofs < 256; ofs <<= 1) {          // inclusive scan
    int cur = 0, add = 0;
    if (t < 256) { cur = pre[t + 1]; if (t + 1 > ofs) add = pre[t + 1 - ofs]; }
    __syncthreads();
    if (t < 256) pre[t + 1] = cur + add;
    __syncthreads();
  }
  if (t < 256) {
    int dst = pre[t], cnt2 = pre[t + 1] - dst;
    int src = ((b << 8) + t) * SEG;
    for (int i = 0; i < cnt2; ++i) feb[dst + i] = elseg[src + i];
  }
  __syncthreads();
  int n = pre[256];

  for (int round = 9; round < ROUNDS && n > 0; ++round) {
    if (t == 0) s_wc = 0;
    __syncthreads();
    for (int base = 0; base < n; base += 1024) {
      int i = base + t;
      bool keep = false; int e = 0; unsigned int pr = 0;
      if (i < n) {
        e = feb[i];
        int u, v; edge_uv(e, u, v);
        int ru = find_root(par, u);
        int rv = find_root(par, v);
        if (par[u] != ru) par[u] = ru;               // compression (root-safe)
        if (par[v] != rv) par[v] = rv;
        if (ru != rv) {
          keep = true;
          pr = ((unsigned int)ru << 16) | (unsigned int)rv;
          ull k = wk[e];
          atomicMin(mb + ru, k);
          atomicMin(mb + rv, k);
        }
      }
      ull msk = __ballot(keep);
      int lane = t & 63, wid = t >> 6;
      if (lane == 0) wofs[wid] = (int)__popcll(msk);
      __syncthreads();                               // all reads of this chunk done
      if (t == 0) {
        int s = s_wc;
#pragma unroll
        for (int k2 = 0; k2 < 16; ++k2) { int c2 = wofs[k2]; wofs[k2] = s; s += c2; }
        s_wc = s;
      }
      __syncthreads();
      if (keep) {                                    // writes land < base+1024
        int pos = wofs[wid] + (int)__popcll(msk & ((1ULL << lane) - 1));
        feb[pos] = e;
        frb[pos] = pr;
      }
    }
    __syncthreads();
    int kept = s_wc;
    for (int i = t; i < kept; i += 1024) {           // winner-claim + hook
      unsigned int pr = frb[i];
      int ru = (int)(pr >> 16), rv = (int)(pr & 0xFFFFu);
      int e = feb[i];
      ull mu = __hip_atomic_load(mb + ru, __ATOMIC_RELAXED, __HIP_MEMORY_SCOPE_AGENT);
      ull mv = __hip_atomic_load(mb + rv, __ATOMIC_RELAXED, __HIP_MEMORY_SCOPE_AGENT);
      bool wu = ((int)(mu & 0xFFFFFFFFu) == e);
      bool wv = ((int)(mv & 0xFFFFFFFFu) == e);
      if (wu | wv) ob[e] = 1.0f;
      if (wu) par[ru] = rv;
      if (wv) par[rv] = ru;
    }
    __syncthreads();
    for (int i = t; i < kept; i += 1024) {           // re-arm dirtied slots
      unsigned int pr = frb[i];
      __hip_atomic_store(mb + (int)(pr >> 16), ~0ULL, __ATOMIC_RELAXED,
                         __HIP_MEMORY_SCOPE_AGENT);
      __hip_atomic_store(mb + (int)(pr & 0xFFFFu), ~0ULL, __ATOMIC_RELAXED,
                         __HIP_MEMORY_SCOPE_AGENT);
    }
    n = kept;
    __syncthreads();
  }
}

} // namespace

extern "C" void kernel_launch(void* const* d_in, const int* in_sizes, int n_in,
                              void* d_out, int out_size, void* d_ws, size_t ws_size,
                              hipStream_t stream) {
  const float* x = (const float*)d_in[0];
  float* out = (float*)d_out;

  char* ws = (char*)d_ws;
  size_t off = 0;
  auto alloc = [&](size_t bytes) {
    void* p = (void*)(ws + off);
    off += (bytes + 255) & ~(size_t)255;
    return p;
  };
  int* parent = (int*)alloc((size_t)B * V * sizeof(int));                      // 1 MB
  int* root   = (int*)alloc((size_t)B * V * sizeof(int));                      // 1 MB
  ull* minE0  = (ull*)alloc((size_t)B * V * 8);                                // 2 MB
  ull* minE1  = (ull*)alloc((size_t)B * V * 8);                                // 2 MB
  ull* wkey   = (ull*)alloc((size_t)B * E * 8);                                // ~5.2 MB
  int* elseg  = (int*)alloc((size_t)NBLKV * SEG * sizeof(int));                // 3 MB
  unsigned int* prblk = (unsigned int*)alloc((size_t)NBLKV * SEG * 4);         // 3 MB
  int* cntblk = (int*)alloc((size_t)NBLKV * sizeof(int));
  int* flags  = (int*)alloc(32 * sizeof(int));
  int* fe     = (int*)alloc((size_t)B * E * sizeof(int));                      // ~2.6 MB
  unsigned int* fr = (unsigned int*)alloc((size_t)B * E * 4);                  // ~2.6 MB

  // 1024-thread blocks: 4 consecutive rows per block -> dn-stream cache reuse
  k_weight5<<<(B * V) / 1024, 1024, 0, stream>>>(x, wkey, out);
  k_r0     <<<(B * V) / 1024, 1024, 0, stream>>>(wkey, minE0, minE1, parent, out, flags);

  // round 1 (per-vertex, minE0)
  k_root  <<<(B * V) / 1024, 1024, 0, stream>>>(parent, root);
  k_vminR1<<<(B * V) / 1024, 1024, 0, stream>>>(root, wkey, minE0);
  k_hookV <<<(B * V) / 1024, 1024, 0, stream>>>(minE0, root, parent, out);

  // round 2 (per-vertex, minE0; seeds round-3 edge frontier; 256-thread SEG)
  k_root  <<<(B * V) / 1024, 1024, 0, stream>>>(parent, root);
  k_vminR2<<<NBLKV, 256, 0, stream>>>(root, wkey, minE0, elseg, cntblk);
  k_hookV <<<(B * V) / 1024, 1024, 0, stream>>>(minE0, root, parent, out);

  // rounds 3..8 (edge frontier, double-buffered minE, endpoint compression)
  for (int r = 3; r <= 8; ++r) {
    ull* mcur  = (r & 1) ? minE0 : minE1;            // r3 -> minE0 (armed)
    ull* mnext = (r & 1) ? minE1 : minE0;
    k_edgeA<<<NBLKV, 256, 0, stream>>>(parent, wkey, mcur, elseg, prblk,
                                       cntblk, flags, r);
    k_edgeB<<<NBLKV, 256, 0, stream>>>(mcur, mnext, elseg, prblk, cntblk,
                                       parent, out, flags, r);
  }

  // rounds 9..16 in one dispatch (minE0 is the armed buffer at r9 entry)
  k_endgame<<<B, 1024, 0, stream>>>(parent, minE0, wkey, out, elseg, cntblk, fe, fr);
}